// Round 2
// baseline (296.060 us; speedup 1.0000x reference)
//
#include <hip/hip_runtime.h>
#include <hip/hip_bf16.h>

typedef __hip_bfloat16 bf16;
typedef __attribute__((ext_vector_type(8))) short short8;   // 8 bf16 = 4 VGPRs (MFMA A/B frag)
typedef __attribute__((ext_vector_type(4))) float f32x4;    // MFMA C/D frag

#define MFMA16(a, b, c) __builtin_amdgcn_mfma_f32_16x16x32_bf16((a), (b), (c), 0, 0, 0)

// ---------------------------------------------------------------------------
// Kernel 1: cast x (fp32) -> bf16, 4 elements/thread
// ---------------------------------------------------------------------------
__global__ __launch_bounds__(256) void cast_x_kernel(const float* __restrict__ in,
                                                     bf16* __restrict__ out) {
    int i = (blockIdx.x * 256 + threadIdx.x) * 4;
    float4 v = *(const float4*)(in + i);
    union { bf16 h4[4]; uint2 u; } p;
    p.h4[0] = __float2bfloat16(v.x);
    p.h4[1] = __float2bfloat16(v.y);
    p.h4[2] = __float2bfloat16(v.z);
    p.h4[3] = __float2bfloat16(v.w);
    *(uint2*)(out + i) = p.u;
}

// ---------------------------------------------------------------------------
// Kernel 2: transpose + cast weights. 64x64 tiles via LDS.
// wq/wk/wv -> WqkvT rows [0,1024)/[1024,2048)/[2048,3072); wo -> WoT.
// Wt[n][k] = W[k][n], bf16.
// ---------------------------------------------------------------------------
__global__ __launch_bounds__(256) void transpose_cast_kernel(
    const float* __restrict__ wq, const float* __restrict__ wk,
    const float* __restrict__ wv, const float* __restrict__ wo,
    bf16* __restrict__ WqkvT, bf16* __restrict__ WoT) {
    __shared__ bf16 tile[64][65];
    int bid = blockIdx.x;
    int mat = bid >> 8;          // 0..3
    int t   = bid & 255;
    int tn  = t >> 4, tk = t & 15;
    const float* src = (mat == 0) ? wq : (mat == 1) ? wk : (mat == 2) ? wv : wo;
    bf16* dst = (mat < 3) ? (WqkvT + (size_t)mat * 1024 * 1024) : WoT;
    int tx = threadIdx.x & 63, ty = threadIdx.x >> 6;
    int k0 = tk * 64, n0 = tn * 64;
#pragma unroll
    for (int p = 0; p < 16; ++p) {
        int r = p * 4 + ty;
        tile[r][tx] = __float2bfloat16(src[(size_t)(k0 + r) * 1024 + n0 + tx]);
    }
    __syncthreads();
#pragma unroll
    for (int p = 0; p < 16; ++p) {
        int r = p * 4 + ty;
        dst[(size_t)(n0 + r) * 1024 + k0 + tx] = tile[tx][r];
    }
}

// ---------------------------------------------------------------------------
// Kernel 3: GEMM1  QKV = Xb[4096,1024] @ WqkvT[3072,1024]^T
//   bn < 16  -> QK bf16 [4096, 2048] (q cols 0..1023, k cols 1024..2047)
//   bn >= 16 -> Vt bf16 [B,H,64,2048] transposed store (8B packed)
// 128x128 block tile, BK=32, 4 waves, 4x4 16x16 MFMA tiles per wave.
// ---------------------------------------------------------------------------
__global__ __launch_bounds__(256) void gemm_qkv_kernel(
    const bf16* __restrict__ A, const bf16* __restrict__ Bt,
    bf16* __restrict__ QK, bf16* __restrict__ Vt) {
    const int K = 1024;
    int bm = blockIdx.x, bn = blockIdx.y;
    __shared__ bf16 As[128 * 32];
    __shared__ bf16 Bs[128 * 32];
    int tid = threadIdx.x;
    int lane = tid & 63, w = tid >> 6;
    int wm = (w >> 1) * 64, wn = (w & 1) * 64;
    int q4 = lane >> 4, li = lane & 15;
    int srow = tid >> 2, sc = (tid & 3) * 8;

    const bf16* Ag = A + (size_t)(bm * 128 + srow) * K + sc;
    const bf16* Bg = Bt + (size_t)(bn * 128 + srow) * K + sc;

    f32x4 acc[4][4];
#pragma unroll
    for (int mt = 0; mt < 4; ++mt)
#pragma unroll
        for (int nt = 0; nt < 4; ++nt) acc[mt][nt] = (f32x4){0.f, 0.f, 0.f, 0.f};

    uint4 ra0 = *(const uint4*)(Ag);
    uint4 ra1 = *(const uint4*)(Ag + 64 * K);
    uint4 rb0 = *(const uint4*)(Bg);
    uint4 rb1 = *(const uint4*)(Bg + 64 * K);

    for (int k0 = 0; k0 < K; k0 += 32) {
        __syncthreads();
        *(uint4*)(As + srow * 32 + sc) = ra0;
        *(uint4*)(As + (srow + 64) * 32 + sc) = ra1;
        *(uint4*)(Bs + srow * 32 + sc) = rb0;
        *(uint4*)(Bs + (srow + 64) * 32 + sc) = rb1;
        __syncthreads();
        if (k0 + 32 < K) {
            ra0 = *(const uint4*)(Ag + k0 + 32);
            ra1 = *(const uint4*)(Ag + 64 * K + k0 + 32);
            rb0 = *(const uint4*)(Bg + k0 + 32);
            rb1 = *(const uint4*)(Bg + 64 * K + k0 + 32);
        }
        short8 af[4], bfb[4];
#pragma unroll
        for (int mt = 0; mt < 4; ++mt)
            af[mt] = *(const short8*)(As + (wm + mt * 16 + li) * 32 + q4 * 8);
#pragma unroll
        for (int nt = 0; nt < 4; ++nt)
            bfb[nt] = *(const short8*)(Bs + (wn + nt * 16 + li) * 32 + q4 * 8);
#pragma unroll
        for (int mt = 0; mt < 4; ++mt)
#pragma unroll
            for (int nt = 0; nt < 4; ++nt)
                acc[mt][nt] = MFMA16(af[mt], bfb[nt], acc[mt][nt]);
    }

    int rowb = bm * 128 + wm;
    if (bn < 16) {
#pragma unroll
        for (int mt = 0; mt < 4; ++mt) {
#pragma unroll
            for (int nt = 0; nt < 4; ++nt) {
                int col = bn * 128 + wn + nt * 16 + li;
#pragma unroll
                for (int r = 0; r < 4; ++r) {
                    int row = rowb + mt * 16 + q4 * 4 + r;
                    QK[(size_t)row * 2048 + col] = __float2bfloat16(acc[mt][nt][r]);
                }
            }
        }
    } else {
#pragma unroll
        for (int mt = 0; mt < 4; ++mt) {
            int sbase = rowb + mt * 16 + q4 * 4;   // global row = b*2048 + s
            int b = sbase >> 11, s = sbase & 2047; // s multiple of 4, no b crossing
#pragma unroll
            for (int nt = 0; nt < 4; ++nt) {
                int n = bn * 128 + wn + nt * 16 + li - 2048;
                int h = n >> 6, d = n & 63;
                union { bf16 h4[4]; uint2 u; } pk;
#pragma unroll
                for (int r = 0; r < 4; ++r) pk.h4[r] = __float2bfloat16(acc[mt][nt][r]);
                *(uint2*)(Vt + (size_t)((b * 16 + h) * 64 + d) * 2048 + s) = pk.u;
            }
        }
    }
}

// ---------------------------------------------------------------------------
// Kernel 4: flash attention with ALiBi + head-0 read-bias.
// Block = (b, h, 64-query tile); 4 waves x 16 rows; j-tiles of 64 keys.
// Head 0 loops the full sequence (getchar rows are NON-causal in the ref).
// Staging: 256 thr x 2 x uint4 = 8 KB per tile (full 64x64 coverage).
// ---------------------------------------------------------------------------
__global__ __launch_bounds__(256) void attn_kernel(
    const bf16* __restrict__ QK, const bf16* __restrict__ Vt,
    const float* __restrict__ x, const float* __restrict__ gch,
    bf16* __restrict__ AO) {
    const int S = 2048;
    int ti = blockIdx.x, h = blockIdx.y, b = blockIdx.z;
    int i0 = ti * 64;
    int tid = threadIdx.x, lane = tid & 63, w = tid >> 6;
    int q4 = lane >> 4, li = lane & 15;

    __shared__ bf16 Ks[64 * 72];      // K tile [j][d], +8 pad
    __shared__ bf16 Vs[64 * 72];      // V^T tile [d][j], +8 pad
    __shared__ bf16 Ps[4][16 * 72];   // per-wave P strip [i][j], +8 pad

    int iw = i0 + w * 16;
    int qrow = b * S + iw + li;
    short8 qf0 = *(const short8*)(QK + (size_t)qrow * 2048 + h * 64 + q4 * 8);
    short8 qf1 = *(const short8*)(QK + (size_t)qrow * 2048 + h * 64 + 32 + q4 * 8);

    float slope = exp2f(-0.5f * (float)(h + 1));
    const float slope0 = 0.70710678118654752f;

    float tgt[4];
    int gc[4];
    if (h == 0) {
#pragma unroll
        for (int r = 0; r < 4; ++r) {
            int iG = iw + q4 * 4 + r;
            int idx = b * S + iG;
            gc[r] = (gch[idx] > 0.5f) ? 1 : 0;
            tgt[r] = x[(size_t)idx * 1024 + 1008] + 1.0f + x[(size_t)idx * 1024 + 1009];
        }
    } else {
#pragma unroll
        for (int r = 0; r < 4; ++r) { gc[r] = 0; tgt[r] = 0.f; }
    }

    float m[4] = {-1e30f, -1e30f, -1e30f, -1e30f};
    float lsum[4] = {0.f, 0.f, 0.f, 0.f};
    f32x4 o[4];
#pragma unroll
    for (int dt = 0; dt < 4; ++dt) o[dt] = (f32x4){0.f, 0.f, 0.f, 0.f};

    // staging indices: 8 threads/row, 2 rows per thread -> full 64x64 tile
    int srow = tid >> 3;          // 0..31
    int scv  = (tid & 7) * 8;     // 0..56
    const bf16* Kg = QK + (size_t)(b * S + srow) * 2048 + 1024 + h * 64 + scv; // j=srow, d=scv
    const bf16* Vg = Vt + (size_t)((b * 16 + h) * 64 + srow) * 2048 + scv;     // d=srow, j=scv

    int ntiles = (h == 0) ? (S / 64) : (ti + 1);
    for (int jt = 0; jt < ntiles; ++jt) {
        int j0 = jt * 64;
        uint4 kv0 = *(const uint4*)(Kg + (size_t)j0 * 2048);
        uint4 kv1 = *(const uint4*)(Kg + (size_t)(j0 + 32) * 2048);
        uint4 vv0 = *(const uint4*)(Vg + j0);
        uint4 vv1 = *(const uint4*)(Vg + (size_t)32 * 2048 + j0);
        __syncthreads();
        *(uint4*)(Ks + srow * 72 + scv) = kv0;
        *(uint4*)(Ks + (srow + 32) * 72 + scv) = kv1;
        *(uint4*)(Vs + srow * 72 + scv) = vv0;
        *(uint4*)(Vs + (srow + 32) * 72 + scv) = vv1;
        __syncthreads();

        f32x4 sAcc[4];
#pragma unroll
        for (int nt = 0; nt < 4; ++nt) sAcc[nt] = (f32x4){0.f, 0.f, 0.f, 0.f};
#pragma unroll
        for (int nt = 0; nt < 4; ++nt) {
            short8 kf0 = *(const short8*)(Ks + (nt * 16 + li) * 72 + q4 * 8);
            short8 kf1 = *(const short8*)(Ks + (nt * 16 + li) * 72 + 32 + q4 * 8);
            sAcc[nt] = MFMA16(qf0, kf0, sAcc[nt]);
            sAcc[nt] = MFMA16(qf1, kf1, sAcc[nt]);
        }

        float p[4][4];   // [nt][r]
#pragma unroll
        for (int nt = 0; nt < 4; ++nt) {
            int jG = j0 + nt * 16 + li;
#pragma unroll
            for (int r = 0; r < 4; ++r) {
                int iG = iw + q4 * 4 + r;
                float sv;
                if (h == 0 && gc[r]) {
                    sv = -slope0 * fabsf(tgt[r] - (float)jG);     // non-causal read bias
                } else {
                    sv = sAcc[nt][r] * 0.125f - slope * (float)(iG - jG);
                    if (jG > iG) sv = -1e30f;
                }
                p[nt][r] = sv;
            }
        }
#pragma unroll
        for (int r = 0; r < 4; ++r) {
            float mx = fmaxf(fmaxf(p[0][r], p[1][r]), fmaxf(p[2][r], p[3][r]));
#pragma unroll
            for (int off = 1; off < 16; off <<= 1) mx = fmaxf(mx, __shfl_xor(mx, off, 64));
            float mn = fmaxf(m[r], mx);
            float alpha = __expf(m[r] - mn);
            m[r] = mn;
            float rs = 0.f;
#pragma unroll
            for (int nt = 0; nt < 4; ++nt) { p[nt][r] = __expf(p[nt][r] - mn); rs += p[nt][r]; }
#pragma unroll
            for (int off = 1; off < 16; off <<= 1) rs += __shfl_xor(rs, off, 64);
            lsum[r] = lsum[r] * alpha + rs;
#pragma unroll
            for (int dt = 0; dt < 4; ++dt) o[dt][r] *= alpha;
        }

        // P: C layout -> A layout via per-wave LDS round trip
        bf16* Pw = &Ps[w][0];
#pragma unroll
        for (int nt = 0; nt < 4; ++nt)
#pragma unroll
            for (int r = 0; r < 4; ++r)
                Pw[(q4 * 4 + r) * 72 + nt * 16 + li] = __float2bfloat16(p[nt][r]);

#pragma unroll
        for (int ks = 0; ks < 2; ++ks) {
            short8 pf = *(const short8*)(Pw + li * 72 + ks * 32 + q4 * 8);
#pragma unroll
            for (int dt = 0; dt < 4; ++dt) {
                short8 vf = *(const short8*)(Vs + (dt * 16 + li) * 72 + ks * 32 + q4 * 8);
                o[dt] = MFMA16(pf, vf, o[dt]);
            }
        }
    }

#pragma unroll
    for (int dt = 0; dt < 4; ++dt) {
#pragma unroll
        for (int r = 0; r < 4; ++r) {
            int iG = iw + q4 * 4 + r;
            float val = o[dt][r] / lsum[r];
            AO[(size_t)(b * S + iG) * 1024 + h * 64 + dt * 16 + li] = __float2bfloat16(val);
        }
    }
}

// ---------------------------------------------------------------------------
// Kernel 5: GEMM2  out = x + AO[4096,1024] @ WoT[1024,1024]^T  (fp32 out)
// ---------------------------------------------------------------------------
__global__ __launch_bounds__(256) void gemm_out_kernel(
    const bf16* __restrict__ A, const bf16* __restrict__ Bt,
    const float* __restrict__ x, float* __restrict__ out) {
    const int K = 1024;
    int bm = blockIdx.x, bn = blockIdx.y;
    __shared__ bf16 As[128 * 32];
    __shared__ bf16 Bs[128 * 32];
    int tid = threadIdx.x;
    int lane = tid & 63, w = tid >> 6;
    int wm = (w >> 1) * 64, wn = (w & 1) * 64;
    int q4 = lane >> 4, li = lane & 15;
    int srow = tid >> 2, sc = (tid & 3) * 8;

    const bf16* Ag = A + (size_t)(bm * 128 + srow) * K + sc;
    const bf16* Bg = Bt + (size_t)(bn * 128 + srow) * K + sc;

    f32x4 acc[4][4];
#pragma unroll
    for (int mt = 0; mt < 4; ++mt)
#pragma unroll
        for (int nt = 0; nt < 4; ++nt) acc[mt][nt] = (f32x4){0.f, 0.f, 0.f, 0.f};

    uint4 ra0 = *(const uint4*)(Ag);
    uint4 ra1 = *(const uint4*)(Ag + 64 * K);
    uint4 rb0 = *(const uint4*)(Bg);
    uint4 rb1 = *(const uint4*)(Bg + 64 * K);

    for (int k0 = 0; k0 < K; k0 += 32) {
        __syncthreads();
        *(uint4*)(As + srow * 32 + sc) = ra0;
        *(uint4*)(As + (srow + 64) * 32 + sc) = ra1;
        *(uint4*)(Bs + srow * 32 + sc) = rb0;
        *(uint4*)(Bs + (srow + 64) * 32 + sc) = rb1;
        __syncthreads();
        if (k0 + 32 < K) {
            ra0 = *(const uint4*)(Ag + k0 + 32);
            ra1 = *(const uint4*)(Ag + 64 * K + k0 + 32);
            rb0 = *(const uint4*)(Bg + k0 + 32);
            rb1 = *(const uint4*)(Bg + 64 * K + k0 + 32);
        }
        short8 af[4], bfb[4];
#pragma unroll
        for (int mt = 0; mt < 4; ++mt)
            af[mt] = *(const short8*)(As + (wm + mt * 16 + li) * 32 + q4 * 8);
#pragma unroll
        for (int nt = 0; nt < 4; ++nt)
            bfb[nt] = *(const short8*)(Bs + (wn + nt * 16 + li) * 32 + q4 * 8);
#pragma unroll
        for (int mt = 0; mt < 4; ++mt)
#pragma unroll
            for (int nt = 0; nt < 4; ++nt)
                acc[mt][nt] = MFMA16(af[mt], bfb[nt], acc[mt][nt]);
    }

#pragma unroll
    for (int mt = 0; mt < 4; ++mt) {
#pragma unroll
        for (int nt = 0; nt < 4; ++nt) {
            int col = bn * 128 + wn + nt * 16 + li;
#pragma unroll
            for (int r = 0; r < 4; ++r) {
                int row = bm * 128 + wm + mt * 16 + q4 * 4 + r;
                size_t idx = (size_t)row * 1024 + col;
                out[idx] = x[idx] + acc[mt][nt][r];
            }
        }
    }
}

// ---------------------------------------------------------------------------
// Kernel 6: I/O channel fixups (io_start = 1008)
// ---------------------------------------------------------------------------
__global__ __launch_bounds__(256) void io_fix_kernel(float* __restrict__ out,
                                                     const float* __restrict__ gch,
                                                     const float* __restrict__ pch) {
    int r = blockIdx.x * 256 + threadIdx.x;   // 0..4095
    float g = gch[r], p = pch[r];
    size_t base = (size_t)r * 1024;
    out[base + 1009] += g;
    out[base + 1011] += p;
    out[base + 1021] = p;
}

// ---------------------------------------------------------------------------
extern "C" void kernel_launch(void* const* d_in, const int* in_sizes, int n_in,
                              void* d_out, int out_size, void* d_ws, size_t ws_size,
                              hipStream_t stream) {
    (void)in_sizes; (void)n_in; (void)out_size; (void)ws_size;
    const float* x   = (const float*)d_in[0];
    const float* gch = (const float*)d_in[1];
    const float* pch = (const float*)d_in[2];
    const float* wq  = (const float*)d_in[3];
    const float* wk  = (const float*)d_in[4];
    const float* wv  = (const float*)d_in[5];
    const float* wo  = (const float*)d_in[6];
    float* out = (float*)d_out;

    char* ws = (char*)d_ws;
    bf16* Xb    = (bf16*)(ws);                      //  8 MB [0,8)
    bf16* WqkvT = (bf16*)(ws + (size_t)( 8 << 20)); //  6 MB [8,14)
    bf16* WoT   = (bf16*)(ws + (size_t)(14 << 20)); //  2 MB [14,16)
    bf16* QK    = (bf16*)(ws + (size_t)(16 << 20)); // 16 MB [16,32)
    bf16* Vt    = (bf16*)(ws + (size_t)(32 << 20)); //  8 MB [32,40)
    bf16* AO    = Xb;  // Xb is dead after gemm_qkv; reuse for attn_out

    cast_x_kernel<<<4096, 256, 0, stream>>>(x, Xb);
    transpose_cast_kernel<<<1024, 256, 0, stream>>>(wq, wk, wv, wo, WqkvT, WoT);
    gemm_qkv_kernel<<<dim3(32, 24), 256, 0, stream>>>(Xb, WqkvT, QK, Vt);
    attn_kernel<<<dim3(32, 16, 2), 256, 0, stream>>>(QK, Vt, x, gch, AO);
    gemm_out_kernel<<<dim3(32, 8), 256, 0, stream>>>(AO, WoT, x, out);
    io_fix_kernel<<<16, 256, 0, stream>>>(out, gch, pch);
}

// Round 3
// 207.914 us; speedup vs baseline: 1.4240x; 1.4240x over previous
//
#include <hip/hip_runtime.h>
#include <hip/hip_bf16.h>

typedef __hip_bfloat16 bf16;
typedef __attribute__((ext_vector_type(8))) short short8;   // 8 bf16 = 4 VGPRs (x32 A/B frag)
typedef __attribute__((ext_vector_type(4))) short short4v;  // 4 bf16 = 2 VGPRs (x16 A/B frag)
typedef __attribute__((ext_vector_type(4))) float f32x4;    // MFMA C/D frag

#define MFMA16(a, b, c) __builtin_amdgcn_mfma_f32_16x16x32_bf16((a), (b), (c), 0, 0, 0)

// 16x16x16 bf16 MFMA: builtin name varies across ROCm; asm fallback.
#if __has_builtin(__builtin_amdgcn_mfma_f32_16x16x16bf16_1k)
#define MFMA_PV(a, b, c) __builtin_amdgcn_mfma_f32_16x16x16bf16_1k((a), (b), (c), 0, 0, 0)
#elif __has_builtin(__builtin_amdgcn_mfma_f32_16x16x16_bf16)
#define MFMA_PV(a, b, c) __builtin_amdgcn_mfma_f32_16x16x16_bf16((a), (b), (c), 0, 0, 0)
#else
static __device__ __forceinline__ f32x4 mfma_pv_asm(short4v a, short4v b, f32x4 c) {
    f32x4 d;
    asm volatile("v_mfma_f32_16x16x16_bf16 %0, %1, %2, %3"
                 : "=&v"(d) : "v"(a), "v"(b), "v"(c));
    return d;
}
#define MFMA_PV(a, b, c) mfma_pv_asm((a), (b), (c))
#endif

// async global->LDS, 16B per lane; LDS dest must be wave-uniform base + lane*16
static __device__ __forceinline__ void gload_lds16(const bf16* g, bf16* l) {
    __builtin_amdgcn_global_load_lds((const __attribute__((address_space(1))) void*)g,
                                     (__attribute__((address_space(3))) void*)l, 16, 0, 0);
}

// ---------------------------------------------------------------------------
// Kernel 1: cast x (fp32) -> bf16
// ---------------------------------------------------------------------------
__global__ __launch_bounds__(256) void cast_x_kernel(const float* __restrict__ in,
                                                     bf16* __restrict__ out) {
    int i = (blockIdx.x * 256 + threadIdx.x) * 4;
    float4 v = *(const float4*)(in + i);
    union { bf16 h4[4]; uint2 u; } p;
    p.h4[0] = __float2bfloat16(v.x);
    p.h4[1] = __float2bfloat16(v.y);
    p.h4[2] = __float2bfloat16(v.z);
    p.h4[3] = __float2bfloat16(v.w);
    *(uint2*)(out + i) = p.u;
}

// ---------------------------------------------------------------------------
// Kernel 2: transpose + cast weights (64x64 LDS tiles)
// ---------------------------------------------------------------------------
__global__ __launch_bounds__(256) void transpose_cast_kernel(
    const float* __restrict__ wq, const float* __restrict__ wk,
    const float* __restrict__ wv, const float* __restrict__ wo,
    bf16* __restrict__ WqkvT, bf16* __restrict__ WoT) {
    __shared__ bf16 tile[64][65];
    int bid = blockIdx.x;
    int mat = bid >> 8;
    int t   = bid & 255;
    int tn  = t >> 4, tk = t & 15;
    const float* src = (mat == 0) ? wq : (mat == 1) ? wk : (mat == 2) ? wv : wo;
    bf16* dst = (mat < 3) ? (WqkvT + (size_t)mat * 1024 * 1024) : WoT;
    int tx = threadIdx.x & 63, ty = threadIdx.x >> 6;
    int k0 = tk * 64, n0 = tn * 64;
#pragma unroll
    for (int p = 0; p < 16; ++p) {
        int r = p * 4 + ty;
        tile[r][tx] = __float2bfloat16(src[(size_t)(k0 + r) * 1024 + n0 + tx]);
    }
    __syncthreads();
#pragma unroll
    for (int p = 0; p < 16; ++p) {
        int r = p * 4 + ty;
        dst[(size_t)(n0 + r) * 1024 + k0 + tx] = tile[tx][r];
    }
}

// ---------------------------------------------------------------------------
// Kernel 3: GEMM1  QKV = Xb @ WqkvT^T, m97-style global_load_lds staging
// ---------------------------------------------------------------------------
__global__ __launch_bounds__(256) void gemm_qkv_kernel(
    const bf16* __restrict__ A, const bf16* __restrict__ Bt,
    bf16* __restrict__ QK, bf16* __restrict__ Vt) {
    const int K = 1024;
    int bm = blockIdx.x, bn = blockIdx.y;
    __shared__ bf16 As[128 * 32];
    __shared__ bf16 Bs[128 * 32];
    int tid = threadIdx.x;
    int lane = tid & 63, w = tid >> 6;
    int wm = (w >> 1) * 64, wn = (w & 1) * 64;
    int q4 = lane >> 4, li = lane & 15;
    int srow = tid >> 2, sc = (tid & 3) * 8;

    const bf16* Ag = A + (size_t)(bm * 128 + srow) * K + sc;
    const bf16* Bg = Bt + (size_t)(bn * 128 + srow) * K + sc;
    bf16* Asl = As + tid * 8;           // row srow, col sc  (lane-contiguous 16B)
    bf16* Asl2 = As + 2048 + tid * 8;   // row srow+64
    bf16* Bsl = Bs + tid * 8;
    bf16* Bsl2 = Bs + 2048 + tid * 8;

    f32x4 acc[4][4];
#pragma unroll
    for (int mt = 0; mt < 4; ++mt)
#pragma unroll
        for (int nt = 0; nt < 4; ++nt) acc[mt][nt] = (f32x4){0.f, 0.f, 0.f, 0.f};

    for (int k0 = 0; k0 < K; k0 += 32) {
        __syncthreads();
        gload_lds16(Ag + k0, Asl);
        gload_lds16(Ag + 64 * K + k0, Asl2);
        gload_lds16(Bg + k0, Bsl);
        gload_lds16(Bg + 64 * K + k0, Bsl2);
        __syncthreads();
        short8 af[4], bfb[4];
#pragma unroll
        for (int mt = 0; mt < 4; ++mt)
            af[mt] = *(const short8*)(As + (wm + mt * 16 + li) * 32 + q4 * 8);
#pragma unroll
        for (int nt = 0; nt < 4; ++nt)
            bfb[nt] = *(const short8*)(Bs + (wn + nt * 16 + li) * 32 + q4 * 8);
#pragma unroll
        for (int mt = 0; mt < 4; ++mt)
#pragma unroll
            for (int nt = 0; nt < 4; ++nt)
                acc[mt][nt] = MFMA16(af[mt], bfb[nt], acc[mt][nt]);
    }

    int rowb = bm * 128 + wm;
    if (bn < 16) {
#pragma unroll
        for (int mt = 0; mt < 4; ++mt) {
#pragma unroll
            for (int nt = 0; nt < 4; ++nt) {
                int col = bn * 128 + wn + nt * 16 + li;
#pragma unroll
                for (int r = 0; r < 4; ++r) {
                    int row = rowb + mt * 16 + q4 * 4 + r;
                    QK[(size_t)row * 2048 + col] = __float2bfloat16(acc[mt][nt][r]);
                }
            }
        }
    } else {
#pragma unroll
        for (int mt = 0; mt < 4; ++mt) {
            int sbase = rowb + mt * 16 + q4 * 4;
            int b = sbase >> 11, s = sbase & 2047;
#pragma unroll
            for (int nt = 0; nt < 4; ++nt) {
                int n = bn * 128 + wn + nt * 16 + li - 2048;
                int h = n >> 6, d = n & 63;
                union { bf16 h4[4]; uint2 u; } pk;
#pragma unroll
                for (int r = 0; r < 4; ++r) pk.h4[r] = __float2bfloat16(acc[mt][nt][r]);
                *(uint2*)(Vt + (size_t)((b * 16 + h) * 64 + d) * 2048 + s) = pk.u;
            }
        }
    }
}

// ---------------------------------------------------------------------------
// Kernel 4: flash attention, S^T formulation, j-sliced waves, LPT schedule.
//  - S^T = K·Q^T via 16x16x32: per-lane C regs are (j=q4*4+r, i=li) == the
//    A-operand layout of P for 16x16x16 PV -> no P LDS round trip.
//  - no-max softmax (scores bounded; shift-invariant), per-lane lsum.
//  - waves own j-slice nt=w of each tile; per-block O reduce through LDS.
// ---------------------------------------------------------------------------
__global__ __launch_bounds__(256, 3) void attn_kernel(
    const bf16* __restrict__ QK, const bf16* __restrict__ Vt,
    const float* __restrict__ x, const float* __restrict__ gch,
    bf16* __restrict__ AO) {
    const int S = 2048;
    // LPT schedule: h=0 blocks (32 tiles) first, then causal descending ti.
    int idx = blockIdx.x;
    int ti, h, b;
    if (idx < 64) { h = 0; b = idx & 1; ti = idx >> 1; }
    else {
        int i2 = idx - 64;
        int row = i2 / 30;
        int j = i2 - row * 30;
        ti = 31 - row; h = 1 + (j >> 1); b = j & 1;
    }
    int i0 = ti * 64;
    int tid = threadIdx.x, lane = tid & 63, w = tid >> 6;
    int q4 = lane >> 4, li = lane & 15;

    __shared__ bf16 Ks[64 * 72];       // K tile [j][d], +8 pad
    __shared__ bf16 Vs[64 * 72];       // V^T tile [d][j], +8 pad
    __shared__ float Ored[64 * 68];    // O reduction buffer [i][d], pitch 68
    __shared__ float lsumBuf[4][64];

    // each wave holds ALL 64 q rows (B-operand frags for S^T)
    short8 qf[4][2];
#pragma unroll
    for (int it = 0; it < 4; ++it) {
        const bf16* qp = QK + (size_t)(b * S + i0 + it * 16 + li) * 2048 + h * 64 + q4 * 8;
        qf[it][0] = *(const short8*)(qp);
        qf[it][1] = *(const short8*)(qp + 32);
    }

    const float L2E = 1.4426950408889634f;
    float slope = exp2f(-0.5f * (float)(h + 1));
    float s1  = 0.125f * L2E;          // 1/sqrt(64) in log2 domain
    float sl1 = slope * L2E;           // coeff of (j - i)
    const float slope0_1 = 0.70710678118654752f * L2E;

    float tgt[4]; int gcm[4];
    if (h == 0) {
#pragma unroll
        for (int it = 0; it < 4; ++it) {
            size_t ix = (size_t)(b * S + i0 + it * 16 + li);
            gcm[it] = gch[ix] > 0.5f ? 1 : 0;
            tgt[it] = x[ix * 1024 + 1008] + 1.0f + x[ix * 1024 + 1009];
        }
    } else {
#pragma unroll
        for (int it = 0; it < 4; ++it) { gcm[it] = 0; tgt[it] = 0.f; }
    }

    float lsum[4] = {0.f, 0.f, 0.f, 0.f};
    f32x4 o[4][4];                     // [it][dt] partial O over wave's j-slice
#pragma unroll
    for (int it = 0; it < 4; ++it)
#pragma unroll
        for (int dt = 0; dt < 4; ++dt) o[it][dt] = (f32x4){0.f, 0.f, 0.f, 0.f};

    int srow = tid >> 3, scv = (tid & 7) * 8;
    const bf16* Kg = QK + (size_t)(b * S + srow) * 2048 + 1024 + h * 64 + scv;
    const bf16* Vg = Vt + (size_t)((b * 16 + h) * 64 + srow) * 2048 + scv;

    int ntiles = (h == 0) ? (S / 64) : (ti + 1);
    for (int jt = 0; jt < ntiles; ++jt) {
        int j0 = jt * 64;
        uint4 kv0 = *(const uint4*)(Kg + (size_t)j0 * 2048);
        uint4 kv1 = *(const uint4*)(Kg + (size_t)(j0 + 32) * 2048);
        uint4 vv0 = *(const uint4*)(Vg + j0);
        uint4 vv1 = *(const uint4*)(Vg + (size_t)32 * 2048 + j0);
        __syncthreads();
        *(uint4*)(Ks + srow * 72 + scv) = kv0;
        *(uint4*)(Ks + (srow + 32) * 72 + scv) = kv1;
        *(uint4*)(Vs + srow * 72 + scv) = vv0;
        *(uint4*)(Vs + (srow + 32) * 72 + scv) = vv1;
        __syncthreads();

        // S^T for wave's j-slice (rows j = j0 + w*16 + q4*4 + r, cols i = li)
        short8 kf0 = *(const short8*)(Ks + (w * 16 + li) * 72 + q4 * 8);
        short8 kf1 = *(const short8*)(Ks + (w * 16 + li) * 72 + 32 + q4 * 8);
        f32x4 sAcc[4];
#pragma unroll
        for (int it = 0; it < 4; ++it) {
            f32x4 z = (f32x4){0.f, 0.f, 0.f, 0.f};
            z = MFMA16(kf0, qf[it][0], z);
            z = MFMA16(kf1, qf[it][1], z);
            sAcc[it] = z;
        }

        float jbase = (float)(j0 + w * 16 + q4 * 4);
        int maskable = (jt >= ti);
        short4v pf[4];
#pragma unroll
        for (int it = 0; it < 4; ++it) {
            float fi = (float)(i0 + it * 16 + li);
            float d0 = jbase - fi;
            union { bf16 hh[4]; short4v v; } pu;
#pragma unroll
            for (int r = 0; r < 4; ++r) {
                float dj = d0 + (float)r;
                float s = fmaf(sl1, dj, sAcc[it][r] * s1);
                float p;
                if (h == 0) {
                    float jj = jbase + (float)r;
                    float sg = -slope0_1 * fabsf(tgt[it] - jj);
                    s = gcm[it] ? sg : s;
                    bool msk = (!gcm[it]) && (dj > 0.f);
                    p = msk ? 0.f : exp2f(s);
                } else {
                    p = exp2f(s);
                    if (maskable && dj > 0.f) p = 0.f;
                }
                lsum[it] += p;
                pu.hh[r] = __float2bfloat16(p);
            }
            pf[it] = pu.v;
        }

        // PV: o[it][dt] += P_slice · V_slice  (16x16x16, A-frag = pf in-regs)
#pragma unroll
        for (int dt = 0; dt < 4; ++dt) {
            short4v vf = *(const short4v*)(Vs + (dt * 16 + li) * 72 + w * 16 + q4 * 4);
#pragma unroll
            for (int it = 0; it < 4; ++it)
                o[it][dt] = MFMA_PV(pf[it], vf, o[it][dt]);
        }
    }

    // finalize lsum (reduce over q4 groups; each lane covers i = it*16+li)
#pragma unroll
    for (int it = 0; it < 4; ++it) {
        lsum[it] += __shfl_xor(lsum[it], 16, 64);
        lsum[it] += __shfl_xor(lsum[it], 32, 64);
    }
    if (lane < 16) {
#pragma unroll
        for (int it = 0; it < 4; ++it) lsumBuf[w][it * 16 + lane] = lsum[it];
    }

    // cross-wave O reduction (serial rounds; o rows are i-local = q4*4+r)
    __syncthreads();
    if (w == 0) {
#pragma unroll
        for (int it = 0; it < 4; ++it)
#pragma unroll
            for (int dt = 0; dt < 4; ++dt)
#pragma unroll
                for (int r = 0; r < 4; ++r)
                    Ored[(it * 16 + q4 * 4 + r) * 68 + dt * 16 + li] = o[it][dt][r];
    }
    __syncthreads();
    if (w == 1) {
#pragma unroll
        for (int it = 0; it < 4; ++it)
#pragma unroll
            for (int dt = 0; dt < 4; ++dt)
#pragma unroll
                for (int r = 0; r < 4; ++r)
                    Ored[(it * 16 + q4 * 4 + r) * 68 + dt * 16 + li] += o[it][dt][r];
    }
    __syncthreads();
    if (w == 2) {
#pragma unroll
        for (int it = 0; it < 4; ++it)
#pragma unroll
            for (int dt = 0; dt < 4; ++dt)
#pragma unroll
                for (int r = 0; r < 4; ++r)
                    Ored[(it * 16 + q4 * 4 + r) * 68 + dt * 16 + li] += o[it][dt][r];
    }
    __syncthreads();
    if (w == 3) {
#pragma unroll
        for (int it = 0; it < 4; ++it)
#pragma unroll
            for (int dt = 0; dt < 4; ++dt)
#pragma unroll
                for (int r = 0; r < 4; ++r)
                    Ored[(it * 16 + q4 * 4 + r) * 68 + dt * 16 + li] += o[it][dt][r];
    }
    __syncthreads();

    // epilogue: thread t -> row i = t>>2, 16-wide d segment
    int i = tid >> 2, dseg = (tid & 3) * 16;
    float ls = lsumBuf[0][i] + lsumBuf[1][i] + lsumBuf[2][i] + lsumBuf[3][i];
    float inv = 1.0f / ls;
    bf16* dst = AO + (size_t)(b * S + i0 + i) * 1024 + h * 64 + dseg;
    union { bf16 hh[16]; uint4 u[2]; } ou;
#pragma unroll
    for (int c = 0; c < 16; ++c)
        ou.hh[c] = __float2bfloat16(Ored[i * 68 + dseg + c] * inv);
    *(uint4*)(dst) = ou.u[0];
    *(uint4*)(dst + 8) = ou.u[1];
}

// ---------------------------------------------------------------------------
// Kernel 5: GEMM2  out = x + AO @ WoT^T (fp32 out), global_load_lds staging
// ---------------------------------------------------------------------------
__global__ __launch_bounds__(256) void gemm_out_kernel(
    const bf16* __restrict__ A, const bf16* __restrict__ Bt,
    const float* __restrict__ x, float* __restrict__ out) {
    const int K = 1024;
    int bm = blockIdx.x, bn = blockIdx.y;
    __shared__ bf16 As[128 * 32];
    __shared__ bf16 Bs[128 * 32];
    int tid = threadIdx.x;
    int lane = tid & 63, w = tid >> 6;
    int wm = (w >> 1) * 64, wn = (w & 1) * 64;
    int q4 = lane >> 4, li = lane & 15;
    int srow = tid >> 2, sc = (tid & 3) * 8;

    const bf16* Ag = A + (size_t)(bm * 128 + srow) * K + sc;
    const bf16* Bg = Bt + (size_t)(bn * 128 + srow) * K + sc;
    bf16* Asl = As + tid * 8;
    bf16* Asl2 = As + 2048 + tid * 8;
    bf16* Bsl = Bs + tid * 8;
    bf16* Bsl2 = Bs + 2048 + tid * 8;

    f32x4 acc[4][4];
#pragma unroll
    for (int mt = 0; mt < 4; ++mt)
#pragma unroll
        for (int nt = 0; nt < 4; ++nt) acc[mt][nt] = (f32x4){0.f, 0.f, 0.f, 0.f};

    for (int k0 = 0; k0 < K; k0 += 32) {
        __syncthreads();
        gload_lds16(Ag + k0, Asl);
        gload_lds16(Ag + 64 * K + k0, Asl2);
        gload_lds16(Bg + k0, Bsl);
        gload_lds16(Bg + 64 * K + k0, Bsl2);
        __syncthreads();
        short8 af[4], bfb[4];
#pragma unroll
        for (int mt = 0; mt < 4; ++mt)
            af[mt] = *(const short8*)(As + (wm + mt * 16 + li) * 32 + q4 * 8);
#pragma unroll
        for (int nt = 0; nt < 4; ++nt)
            bfb[nt] = *(const short8*)(Bs + (wn + nt * 16 + li) * 32 + q4 * 8);
#pragma unroll
        for (int mt = 0; mt < 4; ++mt)
#pragma unroll
            for (int nt = 0; nt < 4; ++nt)
                acc[mt][nt] = MFMA16(af[mt], bfb[nt], acc[mt][nt]);
    }

#pragma unroll
    for (int mt = 0; mt < 4; ++mt) {
#pragma unroll
        for (int nt = 0; nt < 4; ++nt) {
            int col = bn * 128 + wn + nt * 16 + li;
#pragma unroll
            for (int r = 0; r < 4; ++r) {
                int row = bm * 128 + wm + mt * 16 + q4 * 4 + r;
                size_t idx = (size_t)row * 1024 + col;
                out[idx] = x[idx] + acc[mt][nt][r];
            }
        }
    }
}

// ---------------------------------------------------------------------------
// Kernel 6: I/O channel fixups (io_start = 1008)
// ---------------------------------------------------------------------------
__global__ __launch_bounds__(256) void io_fix_kernel(float* __restrict__ out,
                                                     const float* __restrict__ gch,
                                                     const float* __restrict__ pch) {
    int r = blockIdx.x * 256 + threadIdx.x;
    float g = gch[r], p = pch[r];
    size_t base = (size_t)r * 1024;
    out[base + 1009] += g;
    out[base + 1011] += p;
    out[base + 1021] = p;
}

// ---------------------------------------------------------------------------
extern "C" void kernel_launch(void* const* d_in, const int* in_sizes, int n_in,
                              void* d_out, int out_size, void* d_ws, size_t ws_size,
                              hipStream_t stream) {
    (void)in_sizes; (void)n_in; (void)out_size; (void)ws_size;
    const float* x   = (const float*)d_in[0];
    const float* gch = (const float*)d_in[1];
    const float* pch = (const float*)d_in[2];
    const float* wq  = (const float*)d_in[3];
    const float* wk  = (const float*)d_in[4];
    const float* wv  = (const float*)d_in[5];
    const float* wo  = (const float*)d_in[6];
    float* out = (float*)d_out;

    char* ws = (char*)d_ws;
    bf16* Xb    = (bf16*)(ws);
    bf16* WqkvT = (bf16*)(ws + (size_t)( 8 << 20));
    bf16* WoT   = (bf16*)(ws + (size_t)(14 << 20));
    bf16* QK    = (bf16*)(ws + (size_t)(16 << 20));
    bf16* Vt    = (bf16*)(ws + (size_t)(32 << 20));
    bf16* AO    = Xb;  // Xb dead after gemm_qkv

    cast_x_kernel<<<4096, 256, 0, stream>>>(x, Xb);
    transpose_cast_kernel<<<1024, 256, 0, stream>>>(wq, wk, wv, wo, WqkvT, WoT);
    gemm_qkv_kernel<<<dim3(32, 24), 256, 0, stream>>>(Xb, WqkvT, QK, Vt);
    attn_kernel<<<1024, 256, 0, stream>>>(QK, Vt, x, gch, AO);
    gemm_out_kernel<<<dim3(32, 8), 256, 0, stream>>>(AO, WoT, x, out);
    io_fix_kernel<<<16, 256, 0, stream>>>(out, gch, pch);
}